// Round 2
// baseline (25310.027 us; speedup 1.0000x reference)
//
#include <hip/hip_runtime.h>
#include <stdint.h>
#include <stddef.h>

#define T_STEPS 32768
#define HDIM    256
#define NTHR    768

__device__ __forceinline__ float rcpf_(float x) {
#if defined(__has_builtin) && __has_builtin(__builtin_amdgcn_rcpf)
    return __builtin_amdgcn_rcpf(x);     // v_rcp_f32: 1 instr vs ~10-instr exact div
#else
    return 1.0f / x;
#endif
}
__device__ __forceinline__ float sigmoidf_(float x) {
    return rcpf_(1.0f + __expf(-x));
}
__device__ __forceinline__ float tanhf_(float x) {
    float e2 = __expf(2.0f * x);
    return fmaf(-2.0f, rcpf_(e2 + 1.0f), 1.0f);
}

__device__ __forceinline__ int sdot4_(uint32_t a, uint32_t b, int c) {
#if defined(__has_builtin) && __has_builtin(__builtin_amdgcn_sdot4)
    return __builtin_amdgcn_sdot4((int)a, (int)b, c, false);
#else
    int d;
    asm("v_dot4_i32_i8 %0, %1, %2, %3" : "=v"(d) : "v"(a), "v"(b), "v"(c));
    return d;
#endif
}

// VALU-speed partial reduce via DPP row_shr; lane15 of each row16 = row sum.
#define DPPADD(v, CTRL) { \
    int _s = __builtin_amdgcn_update_dpp(0, __builtin_bit_cast(int, v), \
                                         CTRL, 0xf, 0xf, true); \
    v += __builtin_bit_cast(float, _s); }

// |w_hh| <= 1/16 exactly -> fixed scale: q = rint(w * 127/0.0625)
__device__ __forceinline__ uint32_t packw4_(const float4 v) {
    int a = __float2int_rn(v.x * 2032.0f);
    int b = __float2int_rn(v.y * 2032.0f);
    int c = __float2int_rn(v.z * 2032.0f);
    int d = __float2int_rn(v.w * 2032.0f);
    return (uint32_t)(a & 255) | ((uint32_t)(b & 255) << 8) |
           ((uint32_t)(c & 255) << 16) | ((uint32_t)(d & 255) << 24);
}

// 8 named scalar weight dwords (32 int8 weights) per group; 8 groups/row-gate.
#define LWG(pref, G, P, B) \
    uint32_t pref##G##0 = packw4_((P)[(B) + 0]), \
             pref##G##1 = packw4_((P)[(B) + 1]), \
             pref##G##2 = packw4_((P)[(B) + 2]), \
             pref##G##3 = packw4_((P)[(B) + 3]), \
             pref##G##4 = packw4_((P)[(B) + 4]), \
             pref##G##5 = packw4_((P)[(B) + 5]), \
             pref##G##6 = packw4_((P)[(B) + 6]), \
             pref##G##7 = packw4_((P)[(B) + 7]);
#define PING(pref, G) asm volatile("" : \
    "+v"(pref##G##0), "+v"(pref##G##1), "+v"(pref##G##2), "+v"(pref##G##3), \
    "+v"(pref##G##4), "+v"(pref##G##5), "+v"(pref##G##6), "+v"(pref##G##7));

// 8 sdot4 per group over quads QA,QB; 4 rotating accumulator chains
// (dep-use spacing 8 issue-cyc; residual latency hidden by 3 waves/SIMD).
#define DG(G, QA, QB) \
    a0 = sdot4_(w##G##0, (QA).x, a0); a1 = sdot4_(w##G##1, (QA).y, a1); \
    a2 = sdot4_(w##G##2, (QA).z, a2); a3 = sdot4_(w##G##3, (QA).w, a3); \
    a0 = sdot4_(w##G##4, (QB).x, a0); a1 = sdot4_(w##G##5, (QB).y, a1); \
    a2 = sdot4_(w##G##6, (QB).z, a2); a3 = sdot4_(w##G##7, (QB).w, a3);

// R18: 12-wave restructure. R16/R17 plateaued ~22 ms with VALUBusy~61% of the
// one active CU: 1 wave/SIMD can't saturate issue (4-cyc wave rotation vs
// 2-cyc wave64 execute) and 192 weight dwords/thread overflowed the 256-arch-
// VGPR ceiling (VGPR_Count=132 -> rest in AGPRs, per-event accvgpr moves).
// Fix both: 768 threads, ONE gate-row per thread (g=tid>>8: 0=r,1=z,2=n):
//   * 64 weight dwords/thread -> ~115 VGPRs, all-arch, no AGPR traffic.
//   * 3 waves/SIMD -> waves fill each other's issue bubbles; dot floor
//     (192 sdot4 x 2cyc per SIMD) becomes reachable.
//   * combine: z/n threads post pre-activations to LDS -> barrier ->
//     r-threads (tid<256, waves 0-3) do sigmoid/tanh/hnew + hbuf publish ->
//     barrier -> all threads prime next dot. fc-DPP tail stays deferred
//     (r-waves run it while z/n waves sprint into the next scan).
__global__ __launch_bounds__(NTHR, 3)
void aether_gru_kernel(const float* __restrict__ xg,
                       const float* __restrict__ wih,
                       const float* __restrict__ whh,
                       const float* __restrict__ bih,
                       const float* __restrict__ bhh,
                       const float* __restrict__ wfc,
                       const float* __restrict__ bfc,
                       float* __restrict__ out,
                       float* __restrict__ pws_g) {
    const int tid  = threadIdx.x;
    const int lane = tid & 63;
    const int g    = tid >> 8;              // 0=r, 1=z, 2=n (wave-uniform)
    const int ri   = tid & 255;             // row 0..255

    __shared__ float xlds[T_STEPS + 2];
    __shared__ __align__(16) signed char hbuf[2][HDIM];
    __shared__ __align__(16) float pwsL[256 * 16];   // fc partial ring (16 KB)
    __shared__ float idxL[256];                      // event-index ring (1 KB)
    __shared__ float zpreL[256];                     // z pre-activation
    __shared__ float npreL[256];                     // n hidden-side pre

    // ---- stage x into LDS (coalesced float4) ----
    {
        const float4* xs4 = (const float4*)xg;
        float4* xd4 = (float4*)xlds;
        for (int j = tid; j < T_STEPS / 4; j += NTHR)
            xd4[j] = xs4[j];
        if (tid == 0) { xlds[T_STEPS] = 0.0f; xlds[T_STEPS + 1] = 0.0f; }
    }

    // ---- weights: ONE gate-row (64 int8-quad dwords) per thread ----
    const int rowid = g * HDIM + ri;
    const float4* pw = (const float4*)(whh + (size_t)rowid * HDIM);
    LWG(w,A,pw,0)  LWG(w,B,pw,8)  LWG(w,C,pw,16) LWG(w,D,pw,24)
    LWG(w,E,pw,32) LWG(w,F,pw,40) LWG(w,G,pw,48) LWG(w,H,pw,56)
    PING(w,A) PING(w,B) PING(w,C) PING(w,D)
    PING(w,E) PING(w,F) PING(w,G) PING(w,H)

    // per-thread scalar constants
    const float wx = wih[2 * rowid], wd = wih[2 * rowid + 1];
    const float bcomb = (g == 2) ? 0.0f : (bih[rowid] + bhh[rowid]); // folded
    const float cn    = bhh[rowid];          // hidden-side bias (n-threads)
    const float bf    = bfc[0];              // epilogue (all threads)
    // r-threads additionally carry the n-gate INPUT-side scalars + fc weight
    float wxn = 0.0f, wdn = 0.0f, bn = 0.0f, wf = 0.0f;
    if (g == 0) {
        wxn = wih[2 * (2 * HDIM + ri)];
        wdn = wih[2 * (2 * HDIM + ri) + 1];
        bn  = bih[2 * HDIM + ri];
        wf  = wfc[ri];
    }
    const float WSCALE = 0.0625f / 16129.0f; // (1/16/127) * (1/127)

    if (tid < HDIM) hbuf[0][tid] = (signed char)0;
    __syncthreads();

    // ---- sequential state (uniform across threads -> uniform branches) ----
    float hprev    = 0.0f;                  // meaningful in r-threads only
    float last_val = xlds[0] + 1.24f;       // xs[0] + (2*THRESHOLD + 1.0)
    float last_t   = 0.0f;
    int   cnt      = 0;
    int   cur      = 0;

    float xc = xlds[0];
    float xn = xlds[1];

    float* recon = out;
    float* idxp  = out + T_STEPS + 1;

    // prime the 6-quad read-ahead window for the first event
    const uint4* hb = (const uint4*)(&hbuf[0][0]);
    uint4 qa0 = hb[0], qb0 = hb[1];
    uint4 qa1 = hb[2], qb1 = hb[3];
    uint4 qa2 = hb[4], qb2 = hb[5];

    for (int t = 0; t < T_STEPS; ++t) {
        float xf = xlds[t + 2];                      // LDS prefetch, 2 ahead
        const float tf = (float)t;
        const bool ev = fabsf(xc - last_val) >= 0.12f;   // uniform

        if (ev) {
            const float dtv = (tf - last_t) * 0.01f;
            const float gi  = fmaf(wx, xc, fmaf(wd, dtv, bcomb));
            float gin = 0.0f;
            if (g == 0) gin = fmaf(wxn, xc, fmaf(wdn, dtv, bn));

            int a0 = 0, a1 = 0, a2 = 0, a3 = 0;
            DG(A, qa0, qb0)  qa0 = hb[6];  qb0 = hb[7];
            DG(B, qa1, qb1)  qa1 = hb[8];  qb1 = hb[9];
            DG(C, qa2, qb2)  qa2 = hb[10]; qb2 = hb[11];
            DG(D, qa0, qb0)  qa0 = hb[12]; qb0 = hb[13];
            DG(E, qa1, qb1)  qa1 = hb[14]; qb1 = hb[15];
            DG(F, qa2, qb2)
            DG(G, qa0, qb0)
            DG(H, qa1, qb1)
            const int acc = (a0 + a1) + (a2 + a3);

            // pre-activation: r keeps in reg; z/n post to LDS
            const float pre = fmaf((float)acc, WSCALE, (g == 2) ? cn : gi);
            if (g == 1) zpreL[ri] = pre;
            if (g == 2) npreL[ri] = pre;

            __syncthreads();                 // barrier1: zpre/npre visible

            float pv = 0.0f;
            if (g == 0) {
                const float zs = zpreL[ri];
                const float nh = npreL[ri];
                const float r  = sigmoidf_(pre);     // overlaps LDS latency
                const float z  = sigmoidf_(zs);
                const float n  = tanhf_(fmaf(r, nh, gin));
                const float hnew = fmaf(z, hprev, (1.0f - z) * n);
                hprev = hnew;
                // quantize h for next event's dot (|h| < 1 strictly)
                hbuf[cur ^ 1][ri] = (signed char)__float2int_rn(hnew * 127.0f);
                pv = hnew * wf;
            }
            const int   slot = cnt & 255;
            const float tfe  = tf;
            last_val = xc;
            last_t   = tf;
            cnt++;

            __syncthreads();                 // barrier2: hbuf published
            cur ^= 1;
            hb = (const uint4*)(&hbuf[cur][0]);
            // issue next event's first-6 quads NOW (latency hides under
            // deferred tail + scan + gi fmas; other waves fill bubbles)
            qa0 = hb[0]; qb0 = hb[1];
            qa1 = hb[2]; qb1 = hb[3];
            qa2 = hb[4]; qb2 = hb[5];
#if defined(__has_builtin) && __has_builtin(__builtin_amdgcn_sched_barrier)
            __builtin_amdgcn_sched_barrier(0);   // don't let loads sink below
#endif

            // ---- deferred fc tail (r-waves only; z/n waves run ahead) ----
            if (g == 0) {
                DPPADD(pv, 0x111)   // row_shr:1
                DPPADD(pv, 0x112)   // row_shr:2
                DPPADD(pv, 0x114)   // row_shr:4
                DPPADD(pv, 0x118)   // row_shr:8 -> lane15 of row16 = sum
                if ((lane & 15) == 15) pwsL[(slot << 4) | (tid >> 4)] = pv;
                if (tid == 0) idxL[slot] = tfe;
            }

            if (slot == 255) {               // flush full ring chunk (1/256)
                __syncthreads();             // deferred ring writes -> visible
                const int ch = (cnt >> 8) - 1;
                float4* dst = (float4*)(pws_g + ((size_t)ch << 12));
                const float4* src = (const float4*)pwsL;
                for (int i = tid; i < 1024; i += NTHR)
                    dst[i] = src[i];
                if (tid < 256) idxp[(ch << 8) + tid] = idxL[tid];
                __syncthreads();             // protect ring reuse
            }
        }

        xc = xn; xn = xf;
    }

    __syncthreads();    // make last deferred ring writes visible to the flush

    // ---- flush remainder ----
    {
        const int rem  = cnt & 255;
        const int done = cnt - rem;
        if (rem) {
            for (int i = tid; i < (rem << 4); i += NTHR)
                pws_g[((size_t)done << 4) + i] = pwsL[i];
            if (tid < rem) idxp[done + tid] = idxL[tid];
        }
    }
    if (tid == 0) out[T_STEPS] = (float)cnt;          // n_events
    for (int j = cnt + tid; j < T_STEPS; j += NTHR)
        idxp[j] = 32768.0f;                           // pad with T
    __syncthreads();                                  // drain flush stores

    // ---- epilogue: pred per event + piecewise-constant recon fill ----
    for (int k = tid; k < cnt; k += NTHR) {
        const float4* s = (const float4*)(pws_g + ((size_t)k << 4));
        float4 a = s[0], b = s[1], c = s[2], d = s[3];
        float pred = ((a.x + a.y) + (a.z + a.w)) + ((b.x + b.y) + (b.z + b.w))
                   + ((c.x + c.y) + (c.z + c.w)) + ((d.x + d.y) + (d.z + d.w)) + bf;
        const int t0 = (int)idxp[k];
        const int t1 = (k + 1 < cnt) ? (int)idxp[k + 1] : T_STEPS;
        for (int t = t0; t < t1; ++t) recon[t] = pred;
    }
}

extern "C" void kernel_launch(void* const* d_in, const int* in_sizes, int n_in,
                              void* d_out, int out_size, void* d_ws, size_t ws_size,
                              hipStream_t stream) {
    const float* x    = (const float*)d_in[0];
    const float* wih  = (const float*)d_in[1];
    const float* whh  = (const float*)d_in[2];
    const float* bih  = (const float*)d_in[3];
    const float* bhh  = (const float*)d_in[4];
    const float* wfc  = (const float*)d_in[5];
    const float* bfc  = (const float*)d_in[6];
    float* out = (float*)d_out;
    float* pws = (float*)d_ws;   // <= 2 MB (30592 events x 64 B)

    hipLaunchKernelGGL(aether_gru_kernel, dim3(1), dim3(NTHR), 0, stream,
                       x, wih, whh, bih, bhh, wfc, bfc, out, pws);
}

// Round 3
// 24692.299 us; speedup vs baseline: 1.0250x; 1.0250x over previous
//
#include <hip/hip_runtime.h>
#include <stdint.h>
#include <stddef.h>

#define T_STEPS 32768
#define HDIM    256
#define NTHR    768

__device__ __forceinline__ float rcpf_(float x) {
#if defined(__has_builtin) && __has_builtin(__builtin_amdgcn_rcpf)
    return __builtin_amdgcn_rcpf(x);     // v_rcp_f32: 1 instr vs ~10-instr exact div
#else
    return 1.0f / x;
#endif
}
__device__ __forceinline__ float sigmoidf_(float x) {
    return rcpf_(1.0f + __expf(-x));
}
__device__ __forceinline__ float tanhf_(float x) {
    float e2 = __expf(2.0f * x);
    return fmaf(-2.0f, rcpf_(e2 + 1.0f), 1.0f);
}

// R19 KEY CHANGE: sdot4 via inline asm with hard "v" constraints.
// R17/R18 used __builtin_amdgcn_sdot4; the allocator homed the (loop-
// invariant) packed weights in AGPRs (VGPR_Count=68 in R18 despite ~130
// named values) and emitted one v_accvgpr_read PER WEIGHT PER USE
// (~+384 cyc/SIMD/event — measured VALUBusy closes only with this tax).
// v_dot4 can only read arch VGPRs; a "v" constraint at EVERY use site
// makes AGPR homes cost 64 copies/event vs 0 for VGPR homes, and the
// per-thread footprint (~130) fits the 3-wave budget (512/3=170), so the
// allocator should now home weights in arch VGPRs.
__device__ __forceinline__ int sdot4_(uint32_t a, uint32_t b, int c) {
    int d;
    asm("v_dot4_i32_i8 %0, %1, %2, %3"
        : "=v"(d) : "v"(a), "v"(b), "v"(c));
    return d;
}

// VALU-speed partial reduce via DPP row_shr; lane15 of each row16 = row sum.
#define DPPADD(v, CTRL) { \
    int _s = __builtin_amdgcn_update_dpp(0, __builtin_bit_cast(int, v), \
                                         CTRL, 0xf, 0xf, true); \
    v += __builtin_bit_cast(float, _s); }

// |w_hh| <= 1/16 exactly -> fixed scale: q = rint(w * 127/0.0625)
__device__ __forceinline__ uint32_t packw4_(const float4 v) {
    int a = __float2int_rn(v.x * 2032.0f);
    int b = __float2int_rn(v.y * 2032.0f);
    int c = __float2int_rn(v.z * 2032.0f);
    int d = __float2int_rn(v.w * 2032.0f);
    return (uint32_t)(a & 255) | ((uint32_t)(b & 255) << 8) |
           ((uint32_t)(c & 255) << 16) | ((uint32_t)(d & 255) << 24);
}

// 8 named scalar weight dwords (32 int8 weights) per group; 8 groups/row-gate.
#define LWG(pref, G, P, B) \
    uint32_t pref##G##0 = packw4_((P)[(B) + 0]), \
             pref##G##1 = packw4_((P)[(B) + 1]), \
             pref##G##2 = packw4_((P)[(B) + 2]), \
             pref##G##3 = packw4_((P)[(B) + 3]), \
             pref##G##4 = packw4_((P)[(B) + 4]), \
             pref##G##5 = packw4_((P)[(B) + 5]), \
             pref##G##6 = packw4_((P)[(B) + 6]), \
             pref##G##7 = packw4_((P)[(B) + 7]);
#define PING(pref, G) asm volatile("" : \
    "+v"(pref##G##0), "+v"(pref##G##1), "+v"(pref##G##2), "+v"(pref##G##3), \
    "+v"(pref##G##4), "+v"(pref##G##5), "+v"(pref##G##6), "+v"(pref##G##7));

// 8 sdot4 per group over quads QA,QB; 4 rotating accumulator chains
// (dep-use spacing 8 issue-cyc; residual latency hidden by 3 waves/SIMD).
#define DG(G, QA, QB) \
    a0 = sdot4_(w##G##0, (QA).x, a0); a1 = sdot4_(w##G##1, (QA).y, a1); \
    a2 = sdot4_(w##G##2, (QA).z, a2); a3 = sdot4_(w##G##3, (QA).w, a3); \
    a0 = sdot4_(w##G##4, (QB).x, a0); a1 = sdot4_(w##G##5, (QB).y, a1); \
    a2 = sdot4_(w##G##6, (QB).z, a2); a3 = sdot4_(w##G##7, (QB).w, a3);

// R19 = R18 (12-wave, one gate-row/thread) + asm-forced VGPR weight homes.
// Everything else deliberately identical to R18 to isolate the variable.
__global__ __launch_bounds__(NTHR, 3)
void aether_gru_kernel(const float* __restrict__ xg,
                       const float* __restrict__ wih,
                       const float* __restrict__ whh,
                       const float* __restrict__ bih,
                       const float* __restrict__ bhh,
                       const float* __restrict__ wfc,
                       const float* __restrict__ bfc,
                       float* __restrict__ out,
                       float* __restrict__ pws_g) {
    const int tid  = threadIdx.x;
    const int lane = tid & 63;
    const int g    = tid >> 8;              // 0=r, 1=z, 2=n (wave-uniform)
    const int ri   = tid & 255;             // row 0..255

    __shared__ float xlds[T_STEPS + 2];
    __shared__ __align__(16) signed char hbuf[2][HDIM];
    __shared__ __align__(16) float pwsL[256 * 16];   // fc partial ring (16 KB)
    __shared__ float idxL[256];                      // event-index ring (1 KB)
    __shared__ float zpreL[256];                     // z pre-activation
    __shared__ float npreL[256];                     // n hidden-side pre

    // ---- stage x into LDS (coalesced float4) ----
    {
        const float4* xs4 = (const float4*)xg;
        float4* xd4 = (float4*)xlds;
        for (int j = tid; j < T_STEPS / 4; j += NTHR)
            xd4[j] = xs4[j];
        if (tid == 0) { xlds[T_STEPS] = 0.0f; xlds[T_STEPS + 1] = 0.0f; }
    }

    // ---- weights: ONE gate-row (64 int8-quad dwords) per thread ----
    const int rowid = g * HDIM + ri;
    const float4* pw = (const float4*)(whh + (size_t)rowid * HDIM);
    LWG(w,A,pw,0)  LWG(w,B,pw,8)  LWG(w,C,pw,16) LWG(w,D,pw,24)
    LWG(w,E,pw,32) LWG(w,F,pw,40) LWG(w,G,pw,48) LWG(w,H,pw,56)
    PING(w,A) PING(w,B) PING(w,C) PING(w,D)
    PING(w,E) PING(w,F) PING(w,G) PING(w,H)

    // per-thread scalar constants
    const float wx = wih[2 * rowid], wd = wih[2 * rowid + 1];
    const float bcomb = (g == 2) ? 0.0f : (bih[rowid] + bhh[rowid]); // folded
    const float cn    = bhh[rowid];          // hidden-side bias (n-threads)
    const float bf    = bfc[0];              // epilogue (all threads)
    // r-threads additionally carry the n-gate INPUT-side scalars + fc weight
    float wxn = 0.0f, wdn = 0.0f, bn = 0.0f, wf = 0.0f;
    if (g == 0) {
        wxn = wih[2 * (2 * HDIM + ri)];
        wdn = wih[2 * (2 * HDIM + ri) + 1];
        bn  = bih[2 * HDIM + ri];
        wf  = wfc[ri];
    }
    const float WSCALE = 0.0625f / 16129.0f; // (1/16/127) * (1/127)

    if (tid < HDIM) hbuf[0][tid] = (signed char)0;
    __syncthreads();

    // ---- sequential state (uniform across threads -> uniform branches) ----
    float hprev    = 0.0f;                  // meaningful in r-threads only
    float last_val = xlds[0] + 1.24f;       // xs[0] + (2*THRESHOLD + 1.0)
    float last_t   = 0.0f;
    int   cnt      = 0;
    int   cur      = 0;

    float xc = xlds[0];
    float xn = xlds[1];

    float* recon = out;
    float* idxp  = out + T_STEPS + 1;

    // prime the 6-quad read-ahead window for the first event
    const uint4* hb = (const uint4*)(&hbuf[0][0]);
    uint4 qa0 = hb[0], qb0 = hb[1];
    uint4 qa1 = hb[2], qb1 = hb[3];
    uint4 qa2 = hb[4], qb2 = hb[5];

    for (int t = 0; t < T_STEPS; ++t) {
        float xf = xlds[t + 2];                      // LDS prefetch, 2 ahead
        const float tf = (float)t;
        const bool ev = fabsf(xc - last_val) >= 0.12f;   // uniform

        if (ev) {
            const float dtv = (tf - last_t) * 0.01f;
            const float gi  = fmaf(wx, xc, fmaf(wd, dtv, bcomb));
            float gin = 0.0f;
            if (g == 0) gin = fmaf(wxn, xc, fmaf(wdn, dtv, bn));

            int a0 = 0, a1 = 0, a2 = 0, a3 = 0;
            DG(A, qa0, qb0)  qa0 = hb[6];  qb0 = hb[7];
            DG(B, qa1, qb1)  qa1 = hb[8];  qb1 = hb[9];
            DG(C, qa2, qb2)  qa2 = hb[10]; qb2 = hb[11];
            DG(D, qa0, qb0)  qa0 = hb[12]; qb0 = hb[13];
            DG(E, qa1, qb1)  qa1 = hb[14]; qb1 = hb[15];
            DG(F, qa2, qb2)
            DG(G, qa0, qb0)
            DG(H, qa1, qb1)
            const int acc = (a0 + a1) + (a2 + a3);

            // pre-activation: r keeps in reg; z/n post to LDS
            const float pre = fmaf((float)acc, WSCALE, (g == 2) ? cn : gi);
            if (g == 1) zpreL[ri] = pre;
            if (g == 2) npreL[ri] = pre;

            __syncthreads();                 // barrier1: zpre/npre visible

            float pv = 0.0f;
            if (g == 0) {
                const float zs = zpreL[ri];
                const float nh = npreL[ri];
                const float r  = sigmoidf_(pre);     // overlaps LDS latency
                const float z  = sigmoidf_(zs);
                const float n  = tanhf_(fmaf(r, nh, gin));
                const float hnew = fmaf(z, hprev, (1.0f - z) * n);
                hprev = hnew;
                // quantize h for next event's dot (|h| < 1 strictly)
                hbuf[cur ^ 1][ri] = (signed char)__float2int_rn(hnew * 127.0f);
                pv = hnew * wf;
            }
            const int   slot = cnt & 255;
            const float tfe  = tf;
            last_val = xc;
            last_t   = tf;
            cnt++;

            __syncthreads();                 // barrier2: hbuf published
            cur ^= 1;
            hb = (const uint4*)(&hbuf[cur][0]);
            // issue next event's first-6 quads NOW (latency hides under
            // deferred tail + scan + gi fmas; other waves fill bubbles)
            qa0 = hb[0]; qb0 = hb[1];
            qa1 = hb[2]; qb1 = hb[3];
            qa2 = hb[4]; qb2 = hb[5];
#if defined(__has_builtin) && __has_builtin(__builtin_amdgcn_sched_barrier)
            __builtin_amdgcn_sched_barrier(0);   // don't let loads sink below
#endif

            // ---- deferred fc tail (r-waves only; z/n waves run ahead) ----
            if (g == 0) {
                DPPADD(pv, 0x111)   // row_shr:1
                DPPADD(pv, 0x112)   // row_shr:2
                DPPADD(pv, 0x114)   // row_shr:4
                DPPADD(pv, 0x118)   // row_shr:8 -> lane15 of row16 = sum
                if ((lane & 15) == 15) pwsL[(slot << 4) | (tid >> 4)] = pv;
                if (tid == 0) idxL[slot] = tfe;
            }

            if (slot == 255) {               // flush full ring chunk (1/256)
                __syncthreads();             // deferred ring writes -> visible
                const int ch = (cnt >> 8) - 1;
                float4* dst = (float4*)(pws_g + ((size_t)ch << 12));
                const float4* src = (const float4*)pwsL;
                for (int i = tid; i < 1024; i += NTHR)
                    dst[i] = src[i];
                if (tid < 256) idxp[(ch << 8) + tid] = idxL[tid];
                __syncthreads();             // protect ring reuse
            }
        }

        xc = xn; xn = xf;
    }

    __syncthreads();    // make last deferred ring writes visible to the flush

    // ---- flush remainder ----
    {
        const int rem  = cnt & 255;
        const int done = cnt - rem;
        if (rem) {
            for (int i = tid; i < (rem << 4); i += NTHR)
                pws_g[((size_t)done << 4) + i] = pwsL[i];
            if (tid < rem) idxp[done + tid] = idxL[tid];
        }
    }
    if (tid == 0) out[T_STEPS] = (float)cnt;          // n_events
    for (int j = cnt + tid; j < T_STEPS; j += NTHR)
        idxp[j] = 32768.0f;                           // pad with T
    __syncthreads();                                  // drain flush stores

    // ---- epilogue: pred per event + piecewise-constant recon fill ----
    for (int k = tid; k < cnt; k += NTHR) {
        const float4* s = (const float4*)(pws_g + ((size_t)k << 4));
        float4 a = s[0], b = s[1], c = s[2], d = s[3];
        float pred = ((a.x + a.y) + (a.z + a.w)) + ((b.x + b.y) + (b.z + b.w))
                   + ((c.x + c.y) + (c.z + c.w)) + ((d.x + d.y) + (d.z + d.w)) + bf;
        const int t0 = (int)idxp[k];
        const int t1 = (k + 1 < cnt) ? (int)idxp[k + 1] : T_STEPS;
        for (int t = t0; t < t1; ++t) recon[t] = pred;
    }
}

extern "C" void kernel_launch(void* const* d_in, const int* in_sizes, int n_in,
                              void* d_out, int out_size, void* d_ws, size_t ws_size,
                              hipStream_t stream) {
    const float* x    = (const float*)d_in[0];
    const float* wih  = (const float*)d_in[1];
    const float* whh  = (const float*)d_in[2];
    const float* bih  = (const float*)d_in[3];
    const float* bhh  = (const float*)d_in[4];
    const float* wfc  = (const float*)d_in[5];
    const float* bfc  = (const float*)d_in[6];
    float* out = (float*)d_out;
    float* pws = (float*)d_ws;   // <= 2 MB (30592 events x 64 B)

    hipLaunchKernelGGL(aether_gru_kernel, dim3(1), dim3(NTHR), 0, stream,
                       x, wih, whh, bih, bhh, wfc, bfc, out, pws);
}

// Round 4
// 24580.258 us; speedup vs baseline: 1.0297x; 1.0046x over previous
//
#include <hip/hip_runtime.h>
#include <stdint.h>
#include <stddef.h>

#define T_STEPS 32768
#define HDIM    256
#define NTHR    768

__device__ __forceinline__ float rcpf_(float x) {
#if defined(__has_builtin) && __has_builtin(__builtin_amdgcn_rcpf)
    return __builtin_amdgcn_rcpf(x);     // v_rcp_f32: 1 instr vs ~10-instr exact div
#else
    return 1.0f / x;
#endif
}
__device__ __forceinline__ float sigmoidf_(float x) {
    return rcpf_(1.0f + __expf(-x));
}
__device__ __forceinline__ float tanhf_(float x) {
    float e2 = __expf(2.0f * x);
    return fmaf(-2.0f, rcpf_(e2 + 1.0f), 1.0f);
}

__device__ __forceinline__ int sdot4_(uint32_t a, uint32_t b, int c) {
    int d;
    asm("v_dot4_i32_i8 %0, %1, %2, %3"
        : "=v"(d) : "v"(a), "v"(b), "v"(c));
    return d;
}

// VALU-speed partial reduce via DPP row_shr; lane15 of each row16 = row sum.
#define DPPADD(v, CTRL) { \
    int _s = __builtin_amdgcn_update_dpp(0, __builtin_bit_cast(int, v), \
                                         CTRL, 0xf, 0xf, true); \
    v += __builtin_bit_cast(float, _s); }

// |w_hh| <= 1/16 exactly -> fixed scale: q = rint(w * 127/0.0625)
__device__ __forceinline__ uint32_t packw4_(const float4 v) {
    int a = __float2int_rn(v.x * 2032.0f);
    int b = __float2int_rn(v.y * 2032.0f);
    int c = __float2int_rn(v.z * 2032.0f);
    int d = __float2int_rn(v.w * 2032.0f);
    return (uint32_t)(a & 255) | ((uint32_t)(b & 255) << 8) |
           ((uint32_t)(c & 255) << 16) | ((uint32_t)(d & 255) << 24);
}

// 8 named scalar weight dwords (32 int8 weights) per group; 8 groups/row-gate.
#define LWG(pref, G, P, B) \
    uint32_t pref##G##0 = packw4_((P)[(B) + 0]), \
             pref##G##1 = packw4_((P)[(B) + 1]), \
             pref##G##2 = packw4_((P)[(B) + 2]), \
             pref##G##3 = packw4_((P)[(B) + 3]), \
             pref##G##4 = packw4_((P)[(B) + 4]), \
             pref##G##5 = packw4_((P)[(B) + 5]), \
             pref##G##6 = packw4_((P)[(B) + 6]), \
             pref##G##7 = packw4_((P)[(B) + 7]);
#define PING(pref, G) asm volatile("" : \
    "+v"(pref##G##0), "+v"(pref##G##1), "+v"(pref##G##2), "+v"(pref##G##3), \
    "+v"(pref##G##4), "+v"(pref##G##5), "+v"(pref##G##6), "+v"(pref##G##7));

// 8 sdot4 per group over quads QA,QB; 4 rotating accumulator chains
// (dep-use spacing 8 issue-cyc; residual latency hidden by 3 waves/SIMD).
#define DG(G, QA, QB) \
    a0 = sdot4_(w##G##0, (QA).x, a0); a1 = sdot4_(w##G##1, (QA).y, a1); \
    a2 = sdot4_(w##G##2, (QA).z, a2); a3 = sdot4_(w##G##3, (QA).w, a3); \
    a0 = sdot4_(w##G##4, (QB).x, a0); a1 = sdot4_(w##G##5, (QB).y, a1); \
    a2 = sdot4_(w##G##6, (QB).z, a2); a3 = sdot4_(w##G##7, (QB).w, a3);

// R20 = R19 + amdgpu_waves_per_eu(3,3)  [the single changed variable].
// R18/R19 post-mortem: VGPR_Count=68 both rounds. launch_bounds(768,3) only
// sets the waves/EU MINIMUM; the allocator's occupancy heuristic aims at the
// default MAX (~8 waves/EU -> ~64 arch VGPRs), so it homes the 64 packed
// weights in AGPRs (occupancy-free in its gfx908-era cost model) and pays
// one v_accvgpr_read per weight per use (~384 busy-cyc/SIMD/event — the gap
// between static VALU count and measured VALUBusy). Pinning max=3 makes
// shrinking arch usage worthless to the heuristic: budget 512/3=170 arch
// regs >> ~120 demanded -> weights get arch homes, copies vanish.
// FINGERPRINT: VGPR_Count must rise to ~130-170; if it stays 68 the
// register-home theory is dead.
__global__ __launch_bounds__(NTHR)
__attribute__((amdgpu_waves_per_eu(3, 3)))
void aether_gru_kernel(const float* __restrict__ xg,
                       const float* __restrict__ wih,
                       const float* __restrict__ whh,
                       const float* __restrict__ bih,
                       const float* __restrict__ bhh,
                       const float* __restrict__ wfc,
                       const float* __restrict__ bfc,
                       float* __restrict__ out,
                       float* __restrict__ pws_g) {
    const int tid  = threadIdx.x;
    const int lane = tid & 63;
    const int g    = tid >> 8;              // 0=r, 1=z, 2=n (wave-uniform)
    const int ri   = tid & 255;             // row 0..255

    __shared__ float xlds[T_STEPS + 2];
    __shared__ __align__(16) signed char hbuf[2][HDIM];
    __shared__ __align__(16) float pwsL[256 * 16];   // fc partial ring (16 KB)
    __shared__ float idxL[256];                      // event-index ring (1 KB)
    __shared__ float zpreL[256];                     // z pre-activation
    __shared__ float npreL[256];                     // n hidden-side pre

    // ---- stage x into LDS (coalesced float4) ----
    {
        const float4* xs4 = (const float4*)xg;
        float4* xd4 = (float4*)xlds;
        for (int j = tid; j < T_STEPS / 4; j += NTHR)
            xd4[j] = xs4[j];
        if (tid == 0) { xlds[T_STEPS] = 0.0f; xlds[T_STEPS + 1] = 0.0f; }
    }

    // ---- weights: ONE gate-row (64 int8-quad dwords) per thread ----
    const int rowid = g * HDIM + ri;
    const float4* pw = (const float4*)(whh + (size_t)rowid * HDIM);
    LWG(w,A,pw,0)  LWG(w,B,pw,8)  LWG(w,C,pw,16) LWG(w,D,pw,24)
    LWG(w,E,pw,32) LWG(w,F,pw,40) LWG(w,G,pw,48) LWG(w,H,pw,56)
    PING(w,A) PING(w,B) PING(w,C) PING(w,D)
    PING(w,E) PING(w,F) PING(w,G) PING(w,H)

    // per-thread scalar constants
    const float wx = wih[2 * rowid], wd = wih[2 * rowid + 1];
    const float bcomb = (g == 2) ? 0.0f : (bih[rowid] + bhh[rowid]); // folded
    const float cn    = bhh[rowid];          // hidden-side bias (n-threads)
    const float bf    = bfc[0];              // epilogue (all threads)
    // r-threads additionally carry the n-gate INPUT-side scalars + fc weight
    float wxn = 0.0f, wdn = 0.0f, bn = 0.0f, wf = 0.0f;
    if (g == 0) {
        wxn = wih[2 * (2 * HDIM + ri)];
        wdn = wih[2 * (2 * HDIM + ri) + 1];
        bn  = bih[2 * HDIM + ri];
        wf  = wfc[ri];
    }
    const float WSCALE = 0.0625f / 16129.0f; // (1/16/127) * (1/127)

    if (tid < HDIM) hbuf[0][tid] = (signed char)0;
    __syncthreads();

    // ---- sequential state (uniform across threads -> uniform branches) ----
    float hprev    = 0.0f;                  // meaningful in r-threads only
    float last_val = xlds[0] + 1.24f;       // xs[0] + (2*THRESHOLD + 1.0)
    float last_t   = 0.0f;
    int   cnt      = 0;
    int   cur      = 0;

    float xc = xlds[0];
    float xn = xlds[1];

    float* recon = out;
    float* idxp  = out + T_STEPS + 1;

    // prime the 6-quad read-ahead window for the first event
    const uint4* hb = (const uint4*)(&hbuf[0][0]);
    uint4 qa0 = hb[0], qb0 = hb[1];
    uint4 qa1 = hb[2], qb1 = hb[3];
    uint4 qa2 = hb[4], qb2 = hb[5];

    for (int t = 0; t < T_STEPS; ++t) {
        float xf = xlds[t + 2];                      // LDS prefetch, 2 ahead
        const float tf = (float)t;
        const bool ev = fabsf(xc - last_val) >= 0.12f;   // uniform

        if (ev) {
            const float dtv = (tf - last_t) * 0.01f;
            const float gi  = fmaf(wx, xc, fmaf(wd, dtv, bcomb));
            float gin = 0.0f;
            if (g == 0) gin = fmaf(wxn, xc, fmaf(wdn, dtv, bn));

            int a0 = 0, a1 = 0, a2 = 0, a3 = 0;
            DG(A, qa0, qb0)  qa0 = hb[6];  qb0 = hb[7];
            DG(B, qa1, qb1)  qa1 = hb[8];  qb1 = hb[9];
            DG(C, qa2, qb2)  qa2 = hb[10]; qb2 = hb[11];
            DG(D, qa0, qb0)  qa0 = hb[12]; qb0 = hb[13];
            DG(E, qa1, qb1)  qa1 = hb[14]; qb1 = hb[15];
            DG(F, qa2, qb2)
            DG(G, qa0, qb0)
            DG(H, qa1, qb1)
            const int acc = (a0 + a1) + (a2 + a3);

            // pre-activation: r keeps in reg; z/n post to LDS
            const float pre = fmaf((float)acc, WSCALE, (g == 2) ? cn : gi);
            if (g == 1) zpreL[ri] = pre;
            if (g == 2) npreL[ri] = pre;

            __syncthreads();                 // barrier1: zpre/npre visible

            float pv = 0.0f;
            if (g == 0) {
                const float zs = zpreL[ri];
                const float nh = npreL[ri];
                const float r  = sigmoidf_(pre);     // overlaps LDS latency
                const float z  = sigmoidf_(zs);
                const float n  = tanhf_(fmaf(r, nh, gin));
                const float hnew = fmaf(z, hprev, (1.0f - z) * n);
                hprev = hnew;
                // quantize h for next event's dot (|h| < 1 strictly)
                hbuf[cur ^ 1][ri] = (signed char)__float2int_rn(hnew * 127.0f);
                pv = hnew * wf;
            }
            const int   slot = cnt & 255;
            const float tfe  = tf;
            last_val = xc;
            last_t   = tf;
            cnt++;

            __syncthreads();                 // barrier2: hbuf published
            cur ^= 1;
            hb = (const uint4*)(&hbuf[cur][0]);
            // issue next event's first-6 quads NOW (latency hides under
            // deferred tail + scan + gi fmas; other waves fill bubbles)
            qa0 = hb[0]; qb0 = hb[1];
            qa1 = hb[2]; qb1 = hb[3];
            qa2 = hb[4]; qb2 = hb[5];
#if defined(__has_builtin) && __has_builtin(__builtin_amdgcn_sched_barrier)
            __builtin_amdgcn_sched_barrier(0);   // don't let loads sink below
#endif

            // ---- deferred fc tail (r-waves only; z/n waves run ahead) ----
            if (g == 0) {
                DPPADD(pv, 0x111)   // row_shr:1
                DPPADD(pv, 0x112)   // row_shr:2
                DPPADD(pv, 0x114)   // row_shr:4
                DPPADD(pv, 0x118)   // row_shr:8 -> lane15 of row16 = sum
                if ((lane & 15) == 15) pwsL[(slot << 4) | (tid >> 4)] = pv;
                if (tid == 0) idxL[slot] = tfe;
            }

            if (slot == 255) {               // flush full ring chunk (1/256)
                __syncthreads();             // deferred ring writes -> visible
                const int ch = (cnt >> 8) - 1;
                float4* dst = (float4*)(pws_g + ((size_t)ch << 12));
                const float4* src = (const float4*)pwsL;
                for (int i = tid; i < 1024; i += NTHR)
                    dst[i] = src[i];
                if (tid < 256) idxp[(ch << 8) + tid] = idxL[tid];
                __syncthreads();             // protect ring reuse
            }
        }

        xc = xn; xn = xf;
    }

    __syncthreads();    // make last deferred ring writes visible to the flush

    // ---- flush remainder ----
    {
        const int rem  = cnt & 255;
        const int done = cnt - rem;
        if (rem) {
            for (int i = tid; i < (rem << 4); i += NTHR)
                pws_g[((size_t)done << 4) + i] = pwsL[i];
            if (tid < rem) idxp[done + tid] = idxL[tid];
        }
    }
    if (tid == 0) out[T_STEPS] = (float)cnt;          // n_events
    for (int j = cnt + tid; j < T_STEPS; j += NTHR)
        idxp[j] = 32768.0f;                           // pad with T
    __syncthreads();                                  // drain flush stores

    // ---- epilogue: pred per event + piecewise-constant recon fill ----
    for (int k = tid; k < cnt; k += NTHR) {
        const float4* s = (const float4*)(pws_g + ((size_t)k << 4));
        float4 a = s[0], b = s[1], c = s[2], d = s[3];
        float pred = ((a.x + a.y) + (a.z + a.w)) + ((b.x + b.y) + (b.z + b.w))
                   + ((c.x + c.y) + (c.z + c.w)) + ((d.x + d.y) + (d.z + d.w)) + bf;
        const int t0 = (int)idxp[k];
        const int t1 = (k + 1 < cnt) ? (int)idxp[k + 1] : T_STEPS;
        for (int t = t0; t < t1; ++t) recon[t] = pred;
    }
}

extern "C" void kernel_launch(void* const* d_in, const int* in_sizes, int n_in,
                              void* d_out, int out_size, void* d_ws, size_t ws_size,
                              hipStream_t stream) {
    const float* x    = (const float*)d_in[0];
    const float* wih  = (const float*)d_in[1];
    const float* whh  = (const float*)d_in[2];
    const float* bih  = (const float*)d_in[3];
    const float* bhh  = (const float*)d_in[4];
    const float* wfc  = (const float*)d_in[5];
    const float* bfc  = (const float*)d_in[6];
    float* out = (float*)d_out;
    float* pws = (float*)d_ws;   // <= 2 MB (30592 events x 64 B)

    hipLaunchKernelGGL(aether_gru_kernel, dim3(1), dim3(NTHR), 0, stream,
                       x, wih, whh, bih, bhh, wfc, bfc, out, pws);
}